// Round 15
// baseline (104.007 us; speedup 1.0000x reference)
//
#include <hip/hip_runtime.h>
#include <hip/hip_bf16.h>
#include <math.h>

#define NN 8192
#define INF_ 128
#define OUTF 64

typedef __attribute__((ext_vector_type(4))) float f32x4;
typedef __attribute__((ext_vector_type(4))) int i32x4;
typedef __attribute__((ext_vector_type(8))) unsigned short u16x8;
typedef __attribute__((ext_vector_type(8))) __bf16 bf16x8;

__device__ __forceinline__ unsigned short f2bf(float f) {
    unsigned int u = __float_as_uint(f);
    u = (u + 0x7FFFu + ((u >> 16) & 1u)) >> 16;
    return (unsigned short)u;
}

// ---- Kernel 1: Wh = h@W (fp32); f1 = Wh@a1; f2 = Wh@a2; WhT = bf16(Wh)^T [64][8192]
__global__ __launch_bounds__(256) void prep_kernel(
    const float* __restrict__ h, const float* __restrict__ W,
    const float* __restrict__ a, unsigned short* __restrict__ WhT,
    float* __restrict__ f1, float* __restrict__ f2)
{
    __shared__ float W_lds[INF_ * OUTF];
    __shared__ float h_lds[32 * INF_];
    __shared__ unsigned short t_lds[OUTF * 34];

    const int t = threadIdx.x;
    const int rb = blockIdx.x * 32;

    {
        const float4* Ws = (const float4*)W;
        float4* Wd = (float4*)W_lds;
        #pragma unroll
        for (int q = 0; q < 8; ++q) Wd[t + 256 * q] = Ws[t + 256 * q];
        const float4* hs = (const float4*)(h + (size_t)rb * INF_);
        float4* hd = (float4*)h_lds;
        #pragma unroll
        for (int q = 0; q < 4; ++q) hd[t + 256 * q] = hs[t + 256 * q];
    }
    __syncthreads();

    const int lane = t & 63;
    const int w = t >> 6;

    float acc[8];
    #pragma unroll
    for (int q = 0; q < 8; ++q) acc[q] = 0.f;
    for (int k = 0; k < INF_; ++k) {
        const float wv = W_lds[k * OUTF + lane];
        #pragma unroll
        for (int q = 0; q < 8; ++q)
            acc[q] = fmaf(h_lds[(w * 8 + q) * INF_ + k], wv, acc[q]);
    }

    const float a1 = a[lane];
    const float a2 = a[OUTF + lane];
    #pragma unroll
    for (int q = 0; q < 8; ++q) {
        float s1 = acc[q] * a1;
        float s2 = acc[q] * a2;
        #pragma unroll
        for (int m = 1; m < 64; m <<= 1) {
            s1 += __shfl_xor(s1, m, 64);
            s2 += __shfl_xor(s2, m, 64);
        }
        if (lane == 0) {
            f1[rb + w * 8 + q] = s1;
            f2[rb + w * 8 + q] = s2;
        }
        t_lds[lane * 34 + w * 8 + q] = f2bf(acc[q]);
    }
    __syncthreads();
    {
        const int c = t >> 2;
        const int ro = (t & 3) * 8;
        unsigned int pk[4];
        #pragma unroll
        for (int i = 0; i < 4; ++i) {
            const unsigned int lo = t_lds[c * 34 + ro + 2 * i];
            const unsigned int hi = t_lds[c * 34 + ro + 2 * i + 1];
            pk[i] = lo | (hi << 16);
        }
        *(uint4*)(WhT + (size_t)c * NN + rb + ro) = make_uint4(pk[0], pk[1], pk[2], pk[3]);
    }
}

// ---- Kernel 1b: f2max = max_j f2[j]
__global__ __launch_bounds__(1024) void fmax_kernel(
    const float* __restrict__ f2, float* __restrict__ f2max)
{
    __shared__ float red[16];
    const int t = threadIdx.x;
    float m = -INFINITY;
    #pragma unroll
    for (int q = 0; q < NN / 1024; ++q) m = fmaxf(m, f2[t + q * 1024]);
    #pragma unroll
    for (int s = 1; s < 64; s <<= 1) m = fmaxf(m, __shfl_xor(m, s, 64));
    if ((t & 63) == 0) red[t >> 6] = m;
    __syncthreads();
    if (t == 0) {
        float r = red[0];
        #pragma unroll
        for (int i = 1; i < 16; ++i) r = fmaxf(r, red[i]);
        f2max[0] = r;
    }
}

// ---- Kernel 1c: repack WhT into lane-contiguous B-fragments.
__global__ __launch_bounds__(256) void repack_kernel(
    const unsigned short* __restrict__ WhT, unsigned short* __restrict__ WhTs)
{
    const int ch = blockIdx.x;    // 256 chunks of 32 j
    const int t = threadIdx.x;
    const int qd = t >> 6, l = t & 63;
    const int r = l & 15, g = l >> 4;
    const u16x8 v = *(const u16x8*)(WhT + (size_t)(qd * 16 + r) * NN + ch * 32 + g * 8);
    *(u16x8*)(WhTs + (size_t)ch * 2048 + qd * 512 + l * 8) = v;
}

// ---- Kernel 1d: bd[j] = pack(bf16(exp(f2_j)), bf16(exp(0.2*f2_j)))
__global__ __launch_bounds__(1024) void bd_kernel(
    const float* __restrict__ f2, unsigned int* __restrict__ bd)
{
    const int i = blockIdx.x * 1024 + threadIdx.x;
    const float v = f2[i];
    const unsigned int B = f2bf(expf(v));
    const unsigned int D = f2bf(expf(0.2f * v));
    bd[i] = B | (D << 16);
}

// ---- Kernel 2: two-phase block.
// Phase A: each wave streams a CONTIGUOUS 64 KB sub-slab (2 whole adj rows) as
//          sequential 1 KB i32x4 loads -> ballots -> mask bits in LDS.
// Phase B: exp-free table consume; VMEM queue contains ONLY L2 loads (WhTs,bd).
#define MQW 129   // u64 per mask row (128 payload + 1 pad -> bank spread)

__global__ __launch_bounds__(512) void gatp_kernel(
    const int* __restrict__ adj, const unsigned short* __restrict__ WhTs,
    const float* __restrict__ f1, const unsigned int* __restrict__ bd,
    const float* __restrict__ f2max, float* __restrict__ out)
{
    __shared__ unsigned long long mask_lds[16 * MQW]; // 16.5 KB
    __shared__ float acc_lds[8 * 16 * OUTF];          // 32 KB
    __shared__ float l_lds[8 * 16];

    const int t = threadIdx.x;
    const int lane = t & 63;
    const int w = t >> 6;
    const int r = lane & 15;     // A-frag row / D feature
    const int g = lane >> 4;     // k-group
    const int row_base = blockIdx.x * 16;

    // ======== phase A: sequential slab stream + ballot masks ========
    {
        // wave w owns bytes [w*64KB, +64KB) of the block's contiguous 512 KB slab
        const i32x4* src = (const i32x4*)(adj + (size_t)row_base * NN + w * 16384);
        i32x4 st[8];
        #pragma unroll
        for (int k = 0; k < 8; ++k) st[k] = src[k * 64 + lane];

        for (int it = 0; it < 64; ++it) {
            const i32x4 v = st[it & 7];
            if (it + 8 < 64) st[it & 7] = src[(it + 8) * 64 + lane];
            // ballot(v[c]) bit l <-> j_in_row = q*256 + 4l + c
            unsigned long long b0 = __ballot(v[0] > 0);
            unsigned long long b1 = __ballot(v[1] > 0);
            unsigned long long b2 = __ballot(v[2] > 0);
            unsigned long long b3 = __ballot(v[3] > 0);
            const int rr = 2 * w + (it >> 5); // row within block
            const int q = it & 31;            // 256-j chunk within row
            if (lane < 4) {
                unsigned long long x = b0;
                x = (lane == 1) ? b1 : x;
                x = (lane == 2) ? b2 : x;
                x = (lane == 3) ? b3 : x;
                mask_lds[rr * MQW + q * 4 + lane] = x;
            }
        }
    }

    const float f1r = f1[row_base + r];
    float Mr = f1r + f2max[0];
    Mr = fmaxf(Mr, 0.2f * Mr);
    const float A = expf(f1r - Mr);          // e>0 branch row factor
    const float C = expf(0.2f * f1r - Mr);   // e<=0 branch row factor
    const unsigned int THb = (unsigned int)f2bf(expf(-f1r)); // B_j > THb <=> e > 0

    f32x4 accl = {0.f, 0.f, 0.f, 0.f};
    f32x4 acc[4];
    #pragma unroll
    for (int q = 0; q < 4; ++q) acc[q] = accl;

    u16x8 ones_u;
    #pragma unroll
    for (int i = 0; i < 8; ++i) ones_u[i] = 0x3F80;
    const bf16x8 bones = __builtin_bit_cast(bf16x8, ones_u);

    __syncthreads(); // masks visible; adj fully consumed

    // ======== phase B: consume j-window [w*1024, +1024) ========
    {
        const u16x8* wv = (const u16x8*)WhTs + lane; // + (ch*4+qd)*64
        #pragma unroll
        for (int qq = 0; qq < 4; ++qq) {
            const int qg = w * 4 + qq;       // global 256-j chunk
            // lane's row-r masks for this 256-j chunk (4 x u64)
            const unsigned long long mq0 = mask_lds[r * MQW + qg * 4 + 0];
            const unsigned long long mq1 = mask_lds[r * MQW + qg * 4 + 1];
            const unsigned long long mq2 = mask_lds[r * MQW + qg * 4 + 2];
            const unsigned long long mq3 = mask_lds[r * MQW + qg * 4 + 3];
            #pragma unroll
            for (int cq = 0; cq < 8; ++cq) {
                const int ch = qg * 8 + cq;  // global 32-j chunk id
                const int col = ch * 32 + g * 8;
                const unsigned int shq = 8 * cq + 2 * g;
                // bit for element i: (mq[i&3] >> (shq + (i>>2))) & 1
                const unsigned int e0 = (unsigned int)(mq0 >> shq) & 3u;
                const unsigned int e1 = (unsigned int)(mq1 >> shq) & 3u;
                const unsigned int e2 = (unsigned int)(mq2 >> shq) & 3u;
                const unsigned int e3 = (unsigned int)(mq3 >> shq) & 3u;
                const uint4 bq0 = *(const uint4*)(bd + col);
                const uint4 bq1 = *(const uint4*)(bd + col + 4);
                const unsigned int bdv[8] = {bq0.x, bq0.y, bq0.z, bq0.w,
                                             bq1.x, bq1.y, bq1.z, bq1.w};
                const unsigned int eb[4] = {e0, e1, e2, e3};

                u16x8 pb;
                #pragma unroll
                for (int i = 0; i < 8; ++i) {
                    const unsigned int v = bdv[i];
                    const unsigned int bb = v & 0xFFFFu;
                    const bool up = bb > THb;                    // e > 0 ?
                    const unsigned int sel = up ? bb : (v >> 16);
                    const float f = __uint_as_float(sel << 16);  // bf16 -> f32
                    const float as = up ? A : C;
                    const unsigned int bit = (eb[i & 3] >> (i >> 2)) & 1u;
                    const float p = bit ? f * as : 0.f;
                    pb[i] = __builtin_bit_cast(unsigned short, __float2bfloat16(p));
                }

                const bf16x8 af = __builtin_bit_cast(bf16x8, pb);
                #pragma unroll
                for (int qd = 0; qd < 4; ++qd) {
                    const bf16x8 bq = __builtin_bit_cast(bf16x8, wv[((size_t)ch * 4 + qd) * 64]);
                    acc[qd] = __builtin_amdgcn_mfma_f32_16x16x32_bf16(af, bq, acc[qd], 0, 0, 0);
                }
                accl = __builtin_amdgcn_mfma_f32_16x16x32_bf16(af, bones, accl, 0, 0, 0);
            }
        }
    }

    // D layout: col = lane&15 (feature), row = 4*g + q
    if (r == 0) {
        #pragma unroll
        for (int q = 0; q < 4; ++q) l_lds[w * 16 + 4 * g + q] = accl[q];
    }
    #pragma unroll
    for (int q = 0; q < 4; ++q) {
        const int m = 4 * g + q;
        #pragma unroll
        for (int qd = 0; qd < 4; ++qd)
            acc_lds[(w * 16 + m) * OUTF + qd * 16 + r] = acc[qd][q];
    }
    __syncthreads();

    // merge partials across the 8 waves: 1024 outputs, 2 per thread
    {
        #pragma unroll
        for (int hh = 0; hh < 2; ++hh) {
            const int idx = t + hh * 512;
            const int row = idx >> 6;
            const int col = idx & 63;
            float L = 0.f, o = 0.f;
            #pragma unroll
            for (int ww = 0; ww < 8; ++ww) {
                L += l_lds[ww * 16 + row];
                o += acc_lds[(ww * 16 + row) * OUTF + col];
            }
            o /= L;
            o = (o > 0.f) ? o : expm1f(o); // ELU
            out[(size_t)(row_base + row) * OUTF + col] = o;
        }
    }
}

extern "C" void kernel_launch(void* const* d_in, const int* in_sizes, int n_in,
                              void* d_out, int out_size, void* d_ws, size_t ws_size,
                              hipStream_t stream) {
    const float* h = (const float*)d_in[0];
    const int* adj = (const int*)d_in[1];
    const float* W = (const float*)d_in[2];
    const float* a = (const float*)d_in[3];
    float* out = (float*)d_out;

    char* ws = (char*)d_ws;
    unsigned short* WhT = (unsigned short*)ws;                 // 1 MB
    unsigned short* WhTs = (unsigned short*)(ws + (1 << 20));  // 1 MB swizzled
    float* f1 = (float*)(ws + (2 << 20));                      // 32 KB
    float* f2 = f1 + NN;                                       // 32 KB
    float* f2m = f2 + NN;                                      // 4 B
    unsigned int* bd = (unsigned int*)(f2m + 64);              // 32 KB

    prep_kernel<<<NN / 32, 256, 0, stream>>>(h, W, a, WhT, f1, f2);
    fmax_kernel<<<1, 1024, 0, stream>>>(f2, f2m);
    bd_kernel<<<NN / 1024, 1024, 0, stream>>>(f2, bd);
    repack_kernel<<<NN / 32, 256, 0, stream>>>(WhT, WhTs);
    gatp_kernel<<<NN / 16, 512, 0, stream>>>(adj, WhTs, f1, bd, f2m, out);
}

// Round 16
// 79.552 us; speedup vs baseline: 1.3074x; 1.3074x over previous
//
#include <hip/hip_runtime.h>
#include <hip/hip_bf16.h>
#include <math.h>

#define NN 8192
#define INF_ 128
#define OUTF 64

typedef __attribute__((ext_vector_type(4))) float f32x4;
typedef __attribute__((ext_vector_type(2))) int i32x2;
typedef __attribute__((ext_vector_type(8))) unsigned short u16x8;
typedef __attribute__((ext_vector_type(8))) __bf16 bf16x8;

// barrier WITHOUT vmcnt drain: LDS visibility only (lgkmcnt).
#define BAR()                                                    \
    {                                                            \
        asm volatile("s_waitcnt lgkmcnt(0)" ::: "memory");       \
        __builtin_amdgcn_s_barrier();                            \
    }

__device__ __forceinline__ unsigned short f2bf(float f) {
    unsigned int u = __float_as_uint(f);
    u = (u + 0x7FFFu + ((u >> 16) & 1u)) >> 16;
    return (unsigned short)u;
}

// ---- Kernel 1: Wh = h@W (fp32); f1 = Wh@a1; f2 = Wh@a2; WhT = bf16(Wh)^T [64][8192]
__global__ __launch_bounds__(256) void prep_kernel(
    const float* __restrict__ h, const float* __restrict__ W,
    const float* __restrict__ a, unsigned short* __restrict__ WhT,
    float* __restrict__ f1, float* __restrict__ f2)
{
    __shared__ float W_lds[INF_ * OUTF];
    __shared__ float h_lds[32 * INF_];
    __shared__ unsigned short t_lds[OUTF * 34];

    const int t = threadIdx.x;
    const int rb = blockIdx.x * 32;

    {
        const float4* Ws = (const float4*)W;
        float4* Wd = (float4*)W_lds;
        #pragma unroll
        for (int q = 0; q < 8; ++q) Wd[t + 256 * q] = Ws[t + 256 * q];
        const float4* hs = (const float4*)(h + (size_t)rb * INF_);
        float4* hd = (float4*)h_lds;
        #pragma unroll
        for (int q = 0; q < 4; ++q) hd[t + 256 * q] = hs[t + 256 * q];
    }
    __syncthreads();

    const int lane = t & 63;
    const int w = t >> 6;

    float acc[8];
    #pragma unroll
    for (int q = 0; q < 8; ++q) acc[q] = 0.f;
    for (int k = 0; k < INF_; ++k) {
        const float wv = W_lds[k * OUTF + lane];
        #pragma unroll
        for (int q = 0; q < 8; ++q)
            acc[q] = fmaf(h_lds[(w * 8 + q) * INF_ + k], wv, acc[q]);
    }

    const float a1 = a[lane];
    const float a2 = a[OUTF + lane];
    #pragma unroll
    for (int q = 0; q < 8; ++q) {
        float s1 = acc[q] * a1;
        float s2 = acc[q] * a2;
        #pragma unroll
        for (int m = 1; m < 64; m <<= 1) {
            s1 += __shfl_xor(s1, m, 64);
            s2 += __shfl_xor(s2, m, 64);
        }
        if (lane == 0) {
            f1[rb + w * 8 + q] = s1;
            f2[rb + w * 8 + q] = s2;
        }
        t_lds[lane * 34 + w * 8 + q] = f2bf(acc[q]);
    }
    __syncthreads();
    {
        const int c = t >> 2;
        const int ro = (t & 3) * 8;
        unsigned int pk[4];
        #pragma unroll
        for (int i = 0; i < 4; ++i) {
            const unsigned int lo = t_lds[c * 34 + ro + 2 * i];
            const unsigned int hi = t_lds[c * 34 + ro + 2 * i + 1];
            pk[i] = lo | (hi << 16);
        }
        *(uint4*)(WhT + (size_t)c * NN + rb + ro) = make_uint4(pk[0], pk[1], pk[2], pk[3]);
    }
}

// ---- Kernel 1c: repack WhT into lane-contiguous B-fragments.
__global__ __launch_bounds__(256) void repack_kernel(
    const unsigned short* __restrict__ WhT, unsigned short* __restrict__ WhTs)
{
    const int ch = blockIdx.x;    // 256 chunks of 32 j
    const int t = threadIdx.x;
    const int qd = t >> 6, l = t & 63;
    const int r = l & 15, g = l >> 4;
    const u16x8 v = *(const u16x8*)(WhT + (size_t)(qd * 16 + r) * NN + ch * 32 + g * 8);
    *(u16x8*)(WhTs + (size_t)ch * 2048 + qd * 512 + l * 8) = v;
}

// ---- Kernel 1d: bd[j] = pack(bf16(exp(f2_j)), bf16(exp(0.2*f2_j)))
__global__ __launch_bounds__(1024) void bd_kernel(
    const float* __restrict__ f2, unsigned int* __restrict__ bd)
{
    const int i = blockIdx.x * 1024 + threadIdx.x;
    const float v = f2[i];
    const unsigned int B = f2bf(expf(v));
    const unsigned int D = f2bf(expf(0.2f * v));
    bd[i] = B | (D << 16);
}

// ---- Kernel 2: monolithic-wave fusion; row-factor cancellation:
//      P'_ij = up ? B_j : E_i*D_j  (A_i cancels in the softmax ratio).
//      Hot loop builds TWO bit-select matrices (pB, pD) - zero float math -
//      dual MFMA accumulators share B-fragments; row combine once at end.
__global__ __launch_bounds__(512) void gatz_kernel(
    const int* __restrict__ adj, const unsigned short* __restrict__ WhTs,
    const float* __restrict__ f1, const unsigned int* __restrict__ bd,
    float* __restrict__ out)
{
    __shared__ float acc_lds[8 * 16 * OUTF];  // 32 KB partials
    __shared__ unsigned int bd_lds[NN];       // 32 KB (B,D) bf16 pairs
    __shared__ float l_lds[8 * 16];

    const int t = threadIdx.x;
    const int lane = t & 63;
    const int w = t >> 6;
    const int r = lane & 15;     // A-frag row / D feature
    const int g = lane >> 4;     // k-group
    const int row_base = blockIdx.x * 16;

    // stage bd (32 KB) cooperatively
    #pragma unroll
    for (int q = 0; q < 4; ++q)
        ((uint4*)bd_lds)[t + 512 * q] = ((const uint4*)bd)[t + 512 * q];

    const float f1r = f1[row_base + r];
    const unsigned int THb = (unsigned int)f2bf(expf(-f1r)); // B_j > THb <=> e > 0

    // E for the rows this lane's ACCUMULATOR holds (row = 4g+q)
    float Ev[4];
    #pragma unroll
    for (int q = 0; q < 4; ++q)
        Ev[q] = expf(-0.8f * f1[row_base + 4 * g + q]);

    f32x4 alB = {0.f, 0.f, 0.f, 0.f};
    f32x4 alD = alB;
    f32x4 accB[4], accD[4];
    #pragma unroll
    for (int q = 0; q < 4; ++q) { accB[q] = alB; accD[q] = alB; }

    u16x8 ones_u;
    #pragma unroll
    for (int i = 0; i < 8; ++i) ones_u[i] = 0x3F80;
    const bf16x8 bones = __builtin_bit_cast(bf16x8, ones_u);

    // wave w owns j-window [w*1024, w*1024+1024), all 16 rows.
    const int j0 = w * 1024;
    const int* base = adj + (size_t)row_base * NN + j0 + 2 * lane;
    const u16x8* wv = (const u16x8*)WhTs + lane; // + (ch*4+qd)*64

    // stage seg 0: 16 rows x 128 j, lane-contiguous i32x2
    i32x2 st[16];
    #pragma unroll
    for (int rr = 0; rr < 16; ++rr)
        st[rr] = *(const i32x2*)(base + (size_t)rr * NN);

    BAR(); // bd_lds visible; adj loads stay in flight

    for (int s = 0; s < 8; ++s) {
        // ballot transpose: lane keeps the 2x64-bit masks of ITS row r.
        unsigned long long k0 = 0ull, k1 = 0ull;
        #pragma unroll
        for (int rr = 0; rr < 16; ++rr) {
            const i32x2 v = st[rr];
            const unsigned long long b0 = __ballot(v[0] > 0);
            const unsigned long long b1 = __ballot(v[1] > 0);
            if (rr == r) { k0 = b0; k1 = b1; }
        }

        // consume 4 chunks of 32 j - pure bit-select P construction
        #pragma unroll
        for (int cc = 0; cc < 4; ++cc) {
            const int ch = w * 32 + s * 4 + cc;  // global 32-j chunk id
            const int col = ch * 32 + g * 8;
            const unsigned int sh = 16 * cc + 4 * g;
            const unsigned int m0 = (unsigned int)(k0 >> sh) & 0xFu; // even i
            const unsigned int m1 = (unsigned int)(k1 >> sh) & 0xFu; // odd  i

            // issue this chunk's 4 B-fragment loads FIRST (L2)
            u16x8 wq[4];
            #pragma unroll
            for (int qd = 0; qd < 4; ++qd)
                wq[qd] = wv[((size_t)ch * 4 + qd) * 64];

            const uint4 bq0 = *(const uint4*)(bd_lds + col);
            const uint4 bq1 = *(const uint4*)(bd_lds + col + 4);
            const unsigned int bdv[8] = {bq0.x, bq0.y, bq0.z, bq0.w,
                                         bq1.x, bq1.y, bq1.z, bq1.w};

            u16x8 pbB, pbD;
            #pragma unroll
            for (int i = 0; i < 8; ++i) {
                const unsigned int v = bdv[i];
                const unsigned int bb = v & 0xFFFFu;
                const unsigned int bit = (((i & 1) ? m1 : m0) >> (i >> 1)) & 1u;
                const bool up = bb > THb;
                pbB[i] = (bit && up)  ? (unsigned short)bb        : (unsigned short)0;
                pbD[i] = (bit && !up) ? (unsigned short)(v >> 16) : (unsigned short)0;
            }

            const bf16x8 afB = __builtin_bit_cast(bf16x8, pbB);
            const bf16x8 afD = __builtin_bit_cast(bf16x8, pbD);
            #pragma unroll
            for (int qd = 0; qd < 4; ++qd) {
                const bf16x8 bq = __builtin_bit_cast(bf16x8, wq[qd]);
                accB[qd] = __builtin_amdgcn_mfma_f32_16x16x32_bf16(afB, bq, accB[qd], 0, 0, 0);
                accD[qd] = __builtin_amdgcn_mfma_f32_16x16x32_bf16(afD, bq, accD[qd], 0, 0, 0);
            }
            alB = __builtin_amdgcn_mfma_f32_16x16x32_bf16(afB, bones, alB, 0, 0, 0);
            alD = __builtin_amdgcn_mfma_f32_16x16x32_bf16(afD, bones, alD, 0, 0, 0);
        }

        // keep the adj prefetch BEHIND the consume's VMEM in issue order:
        // only VMEM is blocked from crossing (ALU/MFMA/DS free to schedule).
        __builtin_amdgcn_sched_barrier(0x38F);

        if (s + 1 < 8) {
            #pragma unroll
            for (int rr = 0; rr < 16; ++rr)
                st[rr] = *(const i32x2*)(base + (size_t)rr * NN + (s + 1) * 128);
        }
    }

    // D layout: col = lane&15 (feature), row = 4*g + q; combine accB + E*accD
    if (r == 0) {
        #pragma unroll
        for (int q = 0; q < 4; ++q)
            l_lds[w * 16 + 4 * g + q] = alB[q] + Ev[q] * alD[q];
    }
    #pragma unroll
    for (int q = 0; q < 4; ++q) {
        const int m = 4 * g + q;
        #pragma unroll
        for (int qd = 0; qd < 4; ++qd)
            acc_lds[(w * 16 + m) * OUTF + qd * 16 + r] =
                accB[qd][q] + Ev[q] * accD[qd][q];
    }
    __syncthreads();

    // merge partials across the 8 waves: 1024 outputs, 2 per thread
    {
        #pragma unroll
        for (int hh = 0; hh < 2; ++hh) {
            const int idx = t + hh * 512;
            const int row = idx >> 6;
            const int col = idx & 63;
            float L = 0.f, o = 0.f;
            #pragma unroll
            for (int ww = 0; ww < 8; ++ww) {
                L += l_lds[ww * 16 + row];
                o += acc_lds[(ww * 16 + row) * OUTF + col];
            }
            o /= L;
            o = (o > 0.f) ? o : expm1f(o); // ELU
            out[(size_t)(row_base + row) * OUTF + col] = o;
        }
    }
}

extern "C" void kernel_launch(void* const* d_in, const int* in_sizes, int n_in,
                              void* d_out, int out_size, void* d_ws, size_t ws_size,
                              hipStream_t stream) {
    const float* h = (const float*)d_in[0];
    const int* adj = (const int*)d_in[1];
    const float* W = (const float*)d_in[2];
    const float* a = (const float*)d_in[3];
    float* out = (float*)d_out;

    char* ws = (char*)d_ws;
    unsigned short* WhT = (unsigned short*)ws;                 // 1 MB
    unsigned short* WhTs = (unsigned short*)(ws + (1 << 20));  // 1 MB swizzled
    float* f1 = (float*)(ws + (2 << 20));                      // 32 KB
    float* f2 = f1 + NN;                                       // 32 KB
    unsigned int* bd = (unsigned int*)(f2 + NN);               // 32 KB

    prep_kernel<<<NN / 32, 256, 0, stream>>>(h, W, a, WhT, f1, f2);
    bd_kernel<<<NN / 1024, 1024, 0, stream>>>(f2, bd);
    repack_kernel<<<NN / 32, 256, 0, stream>>>(WhT, WhTs);
    gatz_kernel<<<NN / 16, 512, 0, stream>>>(adj, WhTs, f1, bd, out);
}